// Round 4
// baseline (1905.028 us; speedup 1.0000x reference)
//
#include <hip/hip_runtime.h>

#define IMG_N   8
#define IMG_H   512
#define IMG_W   512
#define BLK     32
#define P_CNT   256
#define PSFN    64
#define SENS    1024

// Paired-row weight layout in LDS: for b in [-8,71] (row = b+8 in [0,79]),
// pair = row>>1 (0..39), parity = row&1, acol = a+1 (1..64 used here).
// Element index = pair*WPSTRIDE + acol*2 + parity. Valid b in [-1,63] ->
// rows 7..71 -> pairs 3..35; everything else is structurally zero.
#define WPAIRS   40
#define WPSTRIDE 132
#define NWP      33     // register-resident pairs 3..35

template<int JT> struct TP {
    static constexpr int J0    = JT * 8;
    static constexpr int CMINr = (J0 - 63) >> 1;
    static constexpr int CMIN  = CMINr < 0 ? 0 : CMINr;
    static constexpr int CMAXr = (J0 + 7) >> 1;
    static constexpr int CMAX  = CMAXr > 31 ? 31 : CMAXr;
    static constexpr int PAIR0 = CMIN - (J0 >> 1) + 32;
};

// acc[t] (j = J0+t) at c-step m uses pair PAIR0+m+3-(t>>1); even t -> .y, odd -> .x
// (verified mapping from R2). Pairs outside [3,35] are exact zeros -> trimmed.
template<int JT, int C, int T>
__device__ __forceinline__ void fma_t(float bc, const float2 (&W)[NWP], float (&acc)[8]) {
    constexpr int pair = TP<JT>::PAIR0 + (C - TP<JT>::CMIN) + 3 - (T >> 1);
    if constexpr (pair >= 3 && pair <= 35) {
        if constexpr (T & 1) acc[T] = fmaf(bc, W[pair - 3].x, acc[T]);
        else                 acc[T] = fmaf(bc, W[pair - 3].y, acc[T]);
    }
}

template<int JT, int C>
__device__ __forceinline__ void fma_c(float bc, const float2 (&W)[NWP], float (&acc)[8]) {
    if constexpr (C >= TP<JT>::CMIN && C <= TP<JT>::CMAX) {
        fma_t<JT, C, 0>(bc, W, acc);
        fma_t<JT, C, 1>(bc, W, acc);
        fma_t<JT, C, 2>(bc, W, acc);
        fma_t<JT, C, 3>(bc, W, acc);
        fma_t<JT, C, 4>(bc, W, acc);
        fma_t<JT, C, 5>(bc, W, acc);
        fma_t<JT, C, 6>(bc, W, acc);
        fma_t<JT, C, 7>(bc, W, acc);
    }
}

template<int WV, int C>
__device__ __forceinline__ void fma_all(float bc, const float2 (&W)[NWP], float (&acc)[4][8]) {
    fma_c<WV +  0, C>(bc, W, acc[0]);
    fma_c<WV +  4, C>(bc, W, acc[1]);
    fma_c<WV +  8, C>(bc, W, acc[2]);
    fma_c<WV + 12, C>(bc, W, acc[3]);
}

template<int WV, int C4>
__device__ __forceinline__ void do_c4(const float* __restrict__ brow,
                                      const float2 (&W)[NWP], float (&acc)[4][8]) {
    const float4 b = *(const float4*)&brow[C4 * 4];
    fma_all<WV, C4 * 4 + 0>(b.x, W, acc);
    fma_all<WV, C4 * 4 + 1>(b.y, W, acc);
    fma_all<WV, C4 * 4 + 2>(b.z, W, acc);
    fma_all<WV, C4 * 4 + 3>(b.w, W, acc);
}

// Systolic main phase, 4 tiles fused per wave. Lane l holds fixed PSF column
// a = 63 - lane (acol = 64 - lane). At r-step r, lane l accumulates output
// i = 2r + l for all 4 tiles; accs shift down 2 lanes per r-step; lanes 0,1
// retire i = 2r, 2r+1 each step.
template<int WV>
__device__ __forceinline__ void wave_compute(
    const float* __restrict__ WpT2, const float* __restrict__ blk_s,
    const int lane, const int icen, const int jcen, float* __restrict__ outn)
{
    const int acol = 64 - lane;               // 1..64, always a valid column

    float2 W[NWP];
    #pragma unroll
    for (int q = 0; q < NWP; ++q)
        W[q] = *(const float2*)&WpT2[(q + 3) * WPSTRIDE + acol * 2];
    // Opaque defs: forbid rematerialization -> weights stay in VGPRs.
    #pragma unroll
    for (int q = 0; q < NWP; ++q)
        asm volatile("" : "+v"(W[q].x), "+v"(W[q].y));

    const int sy0 = jcen - 63;
    float acc[4][8];
    #pragma unroll
    for (int u = 0; u < 4; ++u)
        #pragma unroll
        for (int t = 0; t < 8; ++t) acc[u][t] = 0.0f;

    for (int r = 0; r < 32; ++r) {
        const float* brow = &blk_s[r * 32];
        do_c4<WV, 0>(brow, W, acc);
        do_c4<WV, 1>(brow, W, acc);
        do_c4<WV, 2>(brow, W, acc);
        do_c4<WV, 3>(brow, W, acc);
        do_c4<WV, 4>(brow, W, acc);
        do_c4<WV, 5>(brow, W, acc);
        do_c4<WV, 6>(brow, W, acc);
        do_c4<WV, 7>(brow, W, acc);

        // retire completed outputs i = 2r, 2r+1 (lanes 0,1), all 4 tiles
        if (lane < 2) {
            const int sx = icen - 63 + 2 * r + lane;
            float* orow = outn + (size_t)sx * SENS + sy0;
            #pragma unroll
            for (int u = 0; u < 4; ++u) {
                #pragma unroll
                for (int t = 0; t < 8; ++t)
                    atomicAdd(&orow[(WV + 4 * u) * 8 + t], acc[u][t]);
            }
        }
        // shift accs down 2 lanes; inject zeros at lanes 62,63
        if (r < 31) {
            #pragma unroll
            for (int u = 0; u < 4; ++u)
                #pragma unroll
                for (int t = 0; t < 8; ++t) {
                    float v = __shfl_down(acc[u][t], 2, 64);
                    acc[u][t] = (lane >= 62) ? 0.0f : v;
                }
        }
    }
    // flush in-flight outputs i = 62 + lane (lanes 2..63 -> i in [64,125])
    if (lane >= 2) {
        const int sx = icen - 63 + 62 + lane;
        float* orow = outn + (size_t)sx * SENS + sy0;
        #pragma unroll
        for (int u = 0; u < 4; ++u) {
            #pragma unroll
            for (int t = 0; t < 8; ++t)
                atomicAdd(&orow[(WV + 4 * u) * 8 + t], acc[u][t]);
        }
    }
}

__global__ __launch_bounds__(256, 3) void svconv_splat(
    const float* __restrict__ imgs, const float* __restrict__ psf,
    const float* __restrict__ xc, const float* __restrict__ yc,
    float* __restrict__ out)
{
    __shared__ float WpT2[WPAIRS * WPSTRIDE];   // 21120 B
    __shared__ float blk_s[BLK * BLK];          //  4096 B

    const int bid = blockIdx.x;
    const int n = bid >> 8;
    const int p = bid & 255;
    const int bh = p & 15;      // pairs with i / X axis
    const int bw = p >> 4;      // pairs with j / Y axis
    const int tid = threadIdx.x;

    // ---- zero weight LDS (covers all pads) ----
    for (int idx = tid; idx < WPAIRS * WPSTRIDE; idx += 256) WpT2[idx] = 0.0f;

    // ---- load 32x32 image block ----
    const float* src = imgs + ((size_t)n * IMG_H + bh * BLK) * IMG_W + bw * BLK;
    for (int idx = tid; idx < BLK * BLK; idx += 256) {
        int r = idx >> 5, c = idx & 31;
        blk_s[idx] = src[r * IMG_W + c];
    }
    __syncthreads();

    // ---- build Wp (2x2 aggregated PSF) into paired layout ----
    const float* psfp = psf + (size_t)p * PSFN * PSFN;
    for (int idx = tid; idx < 65 * 65; idx += 256) {
        int ai = idx % 65;          // acol = a+1, a in [-1,63]
        int bi = idx / 65;          // b+1, b in [-1,63]
        int a = ai - 1, b = bi - 1;
        float s = 0.0f;
        #pragma unroll
        for (int du = 0; du < 2; ++du)
            #pragma unroll
            for (int dv = 0; dv < 2; ++dv) {
                int x = a + du, y = b + dv;
                if ((unsigned)x < 64u && (unsigned)y < 64u)
                    s += psfp[x * PSFN + y];
            }
        int row = b + 8;
        WpT2[(row >> 1) * WPSTRIDE + ai * 2 + (row & 1)] = s;
    }
    __syncthreads();

    const int wv = tid >> 6;
    const int lane = tid & 63;
    const int icen = 512 + __float2int_rn(xc[p] * 1e6f);
    const int jcen = 512 + __float2int_rn(yc[p] * 1e6f);
    float* const outn = out + ((size_t)n << 20);

    switch (wv) {
    case 0:  wave_compute<0>(WpT2, blk_s, lane, icen, jcen, outn); break;
    case 1:  wave_compute<1>(WpT2, blk_s, lane, icen, jcen, outn); break;
    case 2:  wave_compute<2>(WpT2, blk_s, lane, icen, jcen, outn); break;
    default: wave_compute<3>(WpT2, blk_s, lane, icen, jcen, outn); break;
    }

    // ================= ghost phase: a = -1 (acol 0) =================
    // contributes to even outputs i = 2r + 64 (incl. i=126 which gets ONLY this)
    for (int g = wv; g < 64; g += 4) {
        const int r = g >> 1, jb = g & 1;
        const int j = jb * 64 + lane;
        const float* brow = &blk_s[r * 32];
        float gacc = 0.0f;
        #pragma unroll 4
        for (int c = 0; c < 32; ++c) {
            int row = 2 * c - j + 71;               // b + 8
            row = (row < 0) ? 0 : ((row > 72) ? 72 : row);  // clamped rows are 0
            const float w = WpT2[(row >> 1) * WPSTRIDE + (row & 1)];
            gacc = fmaf(brow[c], w, gacc);
        }
        const int sx = icen + 1 + 2 * r;            // i = 2r+64
        const int sy = jcen - 63 + j;
        atomicAdd(outn + (size_t)sx * SENS + sy, gacc);
    }
}

extern "C" void kernel_launch(void* const* d_in, const int* in_sizes, int n_in,
                              void* d_out, int out_size, void* d_ws, size_t ws_size,
                              hipStream_t stream) {
    const float* imgs = (const float*)d_in[0];
    const float* psf  = (const float*)d_in[1];
    const float* xc   = (const float*)d_in[4];
    const float* yc   = (const float*)d_in[5];
    float* out = (float*)d_out;

    hipMemsetAsync(out, 0, (size_t)out_size * sizeof(float), stream);
    svconv_splat<<<dim3(IMG_N * P_CNT), dim3(256), 0, stream>>>(imgs, psf, xc, yc, out);
}